// Round 6
// baseline (783.562 us; speedup 1.0000x reference)
//
#include <hip/hip_runtime.h>
#include <hip/hip_bf16.h>

typedef unsigned short u16;
typedef unsigned int u32;
typedef unsigned long long u64;
typedef __attribute__((ext_vector_type(8))) short short8;
typedef __attribute__((ext_vector_type(4))) float floatx4;

#if __has_builtin(__builtin_amdgcn_exp2f)
#define EXP2F(x) __builtin_amdgcn_exp2f(x)
#else
#define EXP2F(x) exp2f(x)
#endif

// SCALE * log2(e): softmax runs in base 2, scale pre-folded into Q cast.
#define QSCALE (0.07216878364870323f * 1.4426950408889634f)
#define ROPE_C 0.62286151779f   /* log2(1e6)/32 */

__device__ __forceinline__ u16 f2b(float f) {
    unsigned int x = __builtin_bit_cast(unsigned int, f);
    unsigned int r = (x + 0x7fffu + ((x >> 16) & 1u)) >> 16;   // RNE
    return (u16)r;
}
__device__ __forceinline__ u32 pk2(float a, float b) {
    return (u32)f2b(a) | ((u32)f2b(b) << 16);   // low 16 = a, high 16 = b
}
__device__ __forceinline__ void async16(const void* g, void* l) {
    __builtin_amdgcn_global_load_lds(
        (const __attribute__((address_space(1))) void*)g,
        (__attribute__((address_space(3))) void*)l, 16, 0, 0);
}

// ---------------------------------------------------------------- fused cast
struct CastArgs {
    const float* src[8];
    u16* dst[8];
    float scale[8];
    int startblk[8];
};

__global__ void cast_all_k(CastArgs a)
{
    const int bid = blockIdx.x;
    int s = 0;
#pragma unroll
    for (int i = 1; i < 8; ++i) s += (bid >= a.startblk[i]);
    const long idx = ((long)(bid - a.startblk[s]) * 256 + threadIdx.x) * 4;
    const float4 v = *(const float4*)(a.src[s] + idx);
    const float sc = a.scale[s];
    const u64 pk = (u64)pk2(v.x * sc, v.y * sc)
                 | ((u64)pk2(v.z * sc, v.w * sc) << 32);
    *(u64*)(a.dst[s] + idx) = pk;
}

// ---------------------------------------------------------------- GEMM  C = A(MxK) * B(NxK)^T
// Proven 128x128 / 256-thread / 3-blocks-per-CU structure, T1 bijective XCD
// swizzle (1D grid, wid = (id%8)*(nwg/8)+id/8, m-fastest within XCD chunk).
// EPI 0 (Q merged, N=3072): col<2048 -> QC bf16 (ld 2048); col>=2048 -> RoPE -> QR (ld 1024)
// EPI 1 (KV merged, N=5120): col<2048 -> KC; 2048..3071 -> RoPE -> KR; >=3072 -> V transposed (b,hd,n)
// EPI 2 (final, N=2048): f32 row-major
template<int EPI>
__global__ void __launch_bounds__(256, 3)
gemm_bt(const u16* __restrict__ A, const u16* __restrict__ Bw,
        void* __restrict__ out0, u16* __restrict__ out1, u16* __restrict__ out2,
        int K)
{
    __shared__ u16 As[128 * 64];
    __shared__ u16 Bs[128 * 64];
    const int t = threadIdx.x;
    const int w = t >> 6;
    const int lane = t & 63;
    const int lq = lane >> 4, lr = lane & 15;

    // bijective XCD swizzle (all grids are multiples of 8); nbm = 32 (M=4096)
    const int nwg = gridDim.x;
    const int id = blockIdx.x;
    const int wid = (id & 7) * (nwg >> 3) + (id >> 3);
    const long tileM = (long)(wid & 31) << 7;
    const long tileN = (long)(wid >> 5) << 7;

    const int wm = (w >> 1) * 64, wn = (w & 1) * 64;

    const floatx4 fzero = {0.f, 0.f, 0.f, 0.f};
    floatx4 acc[4][4];
#pragma unroll
    for (int i = 0; i < 4; ++i)
#pragma unroll
        for (int j = 0; j < 4; ++j) acc[i][j] = fzero;

    for (int k0 = 0; k0 < K; k0 += 64) {
#pragma unroll
        for (int r = 0; r < 4; ++r) {
            const int c = r * 256 + t;
            const int row = c >> 3, cc = c & 7;
            const int gcol = ((cc ^ (row & 7)) << 3);
            async16(A + (tileM + row) * (long)K + k0 + gcol, (char*)As + c * 16);
        }
#pragma unroll
        for (int r = 0; r < 4; ++r) {
            const int c = r * 256 + t;
            const int row = c >> 3, cc = c & 7;
            const int gcol = ((cc ^ (row & 7)) << 3);
            async16(Bw + (tileN + row) * (long)K + k0 + gcol, (char*)Bs + c * 16);
        }
        __builtin_amdgcn_s_waitcnt(0);
        __syncthreads();
#pragma unroll
        for (int kk = 0; kk < 2; ++kk) {
            short8 af[4], bfr[4];
#pragma unroll
            for (int i = 0; i < 4; ++i) {
                const int row = wm + 16 * i + lr;
                const int cc = (kk * 4 + lq) ^ (row & 7);
                af[i] = *(const short8*)(As + row * 64 + cc * 8);
            }
#pragma unroll
            for (int j = 0; j < 4; ++j) {
                const int row = wn + 16 * j + lr;
                const int cc = (kk * 4 + lq) ^ (row & 7);
                bfr[j] = *(const short8*)(Bs + row * 64 + cc * 8);
            }
            __builtin_amdgcn_s_setprio(1);
#pragma unroll
            for (int i = 0; i < 4; ++i)
#pragma unroll
                for (int j = 0; j < 4; ++j)
                    acc[i][j] = __builtin_amdgcn_mfma_f32_16x16x32_bf16(
                        af[i], bfr[j], acc[i][j], 0, 0, 0);
            __builtin_amdgcn_s_setprio(0);
        }
        __syncthreads();
    }

    // ---- epilogue (region is block-uniform: boundaries are multiples of 128)
    const bool isV    = (EPI == 1) && (tileN >= 3072);
    const bool isRope = (EPI != 2) && !isV && (tileN >= 2048);

#pragma unroll
    for (int i = 0; i < 4; ++i) {
#pragma unroll
        for (int j = 0; j < 4; ++j) {
            const long row0 = tileM + wm + 16 * i + 4 * lq;
            const long col  = tileN + wn + 16 * j + lr;
            if (EPI == 2) {
#pragma unroll
                for (int r = 0; r < 4; ++r)
                    ((float*)out0)[(row0 + r) * 2048 + col] = acc[i][j][r];
            } else if (isV) {
                const u32 lo = pk2(acc[i][j][0], acc[i][j][1]);
                const u32 hi = pk2(acc[i][j][2], acc[i][j][3]);
                const long bb = row0 >> 11;
                u16* dst = out2 + ((bb * 2048 + (col - 3072)) << 11) + (row0 & 2047);
                *(uint2*)dst = make_uint2(lo, hi);
            } else if (isRope) {
                const int jj = ((int)col & 63) >> 1;
                const float freq = EXP2F(-ROPE_C * (float)jj);
#pragma unroll
                for (int r = 0; r < 4; ++r) {
                    const float v = acc[i][j][r];
                    const float vp = __shfl_xor(v, 1, 64);
                    const long row = row0 + r;
                    float sn, cs;
                    __sincosf((float)(row & 2047) * freq, &sn, &cs);
                    const float o = (col & 1) ? (v * cs + vp * sn) : (v * cs - vp * sn);
                    out1[row * 1024 + (col - 2048)] = f2b(o);
                }
            } else {
#pragma unroll
                for (int r = 0; r < 4; ++r)
                    ((u16*)out0)[(row0 + r) * 2048 + col] = f2b(acc[i][j][r]);
            }
        }
    }
}

// ---------------------------------------------------------------- flash attention (S^T dataflow)
// grid (16, 16, 2), 256 threads (4 waves), wave owns a 32-row Q strip.
// XCD remap: h = 2*(x&7) + (y&1), qx = 8*(x>>3) + (y>>1) (bijective) — all 16
// Q-tiles of a head on one XCD so its K/V panels stay in that XCD's L2.
// LDS 40960 B -> 4 blocks/CU: P_s aliases the KC region (KC/KR only live in
// QK^T phase; P only in PV phase; one extra __syncthreads separates them).
// P layout: [row][col8^(row&7) blocks of 8] stride 64 — same conflict-free
// XOR scheme as the K/V reads (old stride-72 layout was the 7.3M-conflict src).
__global__ void __launch_bounds__(256, 4)
flash_attn(const u16* __restrict__ QC, const u16* __restrict__ QR,
           const u16* __restrict__ KC, const u16* __restrict__ KR,
           const u16* __restrict__ VT, u16* __restrict__ Obuf)
{
    __shared__ u16 KV_s[64 * 128 + 64 * 64];  // KC @0 (16KB), KR @8192 elem (8KB); P aliases KC
    __shared__ u16 VT_s[128 * 64];            // 16KB

    const int t = threadIdx.x;
    const int w = t >> 6;
    const int lane = t & 63;
    const int lq = lane >> 4, lr = lane & 15;
    const int bx = blockIdx.x, by = blockIdx.y;
    const int h  = ((bx & 7) << 1) | (by & 1);     // head: fixed x&7 -> fixed XCD
    const int qx = ((bx >> 3) << 3) | (by >> 1);   // Q tile index 0..15
    const int mbase = qx * 128 + w * 32;
    const int b = blockIdx.z;

    // Q fragments (Y-operand layout [m=lane&15][k=lq*8+j]) in registers
    short8 aq[2][6];
#pragma unroll
    for (int i = 0; i < 2; ++i) {
        const long m = mbase + 16 * i + lr;
        const u16* qc = QC + ((long)b * 2048 + m) * 2048 + h * 128;
        const u16* qr = QR + ((long)b * 2048 + m) * 1024 + h * 64;
#pragma unroll
        for (int kc = 0; kc < 4; ++kc) aq[i][kc]     = *(const short8*)(qc + kc * 32 + lq * 8);
#pragma unroll
        for (int kc = 0; kc < 2; ++kc) aq[i][4 + kc] = *(const short8*)(qr + kc * 32 + lq * 8);
    }

    const floatx4 fzero = {0.f, 0.f, 0.f, 0.f};
    float mst[2], lst[2];
    floatx4 oacc[2][8];   // O^T: rows d (tile jn, 4lq+r), cols m = lr (strip i)
#pragma unroll
    for (int i = 0; i < 2; ++i) {
        mst[i] = -1e30f; lst[i] = 0.f;
#pragma unroll
        for (int jn = 0; jn < 8; ++jn) oacc[i][jn] = fzero;
    }

    const u16* kc_g = KC + ((long)b * 2048) * 2048 + h * 128;
    const u16* kr_g = KR + ((long)b * 2048) * 1024 + h * 64;
    const u16* vt_g = VT + ((long)(b * 16 + h) * 128) * 2048;

    for (int kt = 0; kt < 32; ++kt) {
#pragma unroll
        for (int r = 0; r < 4; ++r) {
            const int c = r * 256 + t;
            const int krow = c >> 4, cc = c & 15;
            const int gc = cc ^ (krow & 7);
            async16(kc_g + (long)(kt * 64 + krow) * 2048 + gc * 8, (char*)KV_s + c * 16);
        }
#pragma unroll
        for (int r = 0; r < 2; ++r) {
            const int c = r * 256 + t;
            const int krow = c >> 3, cc = c & 7;
            const int gc = cc ^ (krow & 7);
            async16(kr_g + (long)(kt * 64 + krow) * 1024 + gc * 8, (char*)KV_s + 16384 + c * 16);
        }
#pragma unroll
        for (int r = 0; r < 4; ++r) {
            const int c = r * 256 + t;
            const int drow = c >> 3, cc = c & 7;
            const int gc = cc ^ (drow & 7);
            async16(vt_g + (long)drow * 2048 + kt * 64 + gc * 8, (char*)VT_s + c * 16);
        }
        __builtin_amdgcn_s_waitcnt(0);
        __syncthreads();

        // ---- S^T = K Q^T: sT[j][i] rows n (16j+4lq+r), cols m (16i, lane lr)
        floatx4 sT[4][2];
#pragma unroll
        for (int j = 0; j < 4; ++j)
#pragma unroll
            for (int i = 0; i < 2; ++i) sT[j][i] = fzero;
#pragma unroll
        for (int kc = 0; kc < 6; ++kc) {
            short8 kf[4];
#pragma unroll
            for (int j = 0; j < 4; ++j) {
                const int krow = 16 * j + lr;
                if (kc < 4) {
                    const int cc = (4 * kc + lq) ^ (krow & 7);
                    kf[j] = *(const short8*)(KV_s + krow * 128 + cc * 8);
                } else {
                    const int cc = (4 * (kc - 4) + lq) ^ (krow & 7);
                    kf[j] = *(const short8*)(KV_s + 8192 + krow * 64 + cc * 8);
                }
            }
            __builtin_amdgcn_s_setprio(1);
#pragma unroll
            for (int j = 0; j < 4; ++j)
#pragma unroll
                for (int i = 0; i < 2; ++i)
                    sT[j][i] = __builtin_amdgcn_mfma_f32_16x16x32_bf16(
                        kf[j], aq[i][kc], sT[j][i], 0, 0, 0);
            __builtin_amdgcn_s_setprio(0);
        }

        // ---- online softmax: per-lane over 16 regs, then 2 shuffle rounds (lq groups)
        float rmax[2];
#pragma unroll
        for (int i = 0; i < 2; ++i) {
            float a0 = fmaxf(fmaxf(sT[0][i][0], sT[0][i][1]), fmaxf(sT[0][i][2], sT[0][i][3]));
            float a1 = fmaxf(fmaxf(sT[1][i][0], sT[1][i][1]), fmaxf(sT[1][i][2], sT[1][i][3]));
            float a2 = fmaxf(fmaxf(sT[2][i][0], sT[2][i][1]), fmaxf(sT[2][i][2], sT[2][i][3]));
            float a3 = fmaxf(fmaxf(sT[3][i][0], sT[3][i][1]), fmaxf(sT[3][i][2], sT[3][i][3]));
            rmax[i] = fmaxf(fmaxf(a0, a1), fmaxf(a2, a3));
        }
#pragma unroll
        for (int i = 0; i < 2; ++i) {
            rmax[i] = fmaxf(rmax[i], __shfl_xor(rmax[i], 16, 64));
            rmax[i] = fmaxf(rmax[i], __shfl_xor(rmax[i], 32, 64));
        }

        // T13 defer-max: only rescale when max grew by >8 (P bounded by 2^8, bf16-safe)
        const int upd = (rmax[0] > mst[0] + 8.f) | (rmax[1] > mst[1] + 8.f);
        if (__any(upd)) {
#pragma unroll
            for (int i = 0; i < 2; ++i) {
                const float mnew = fmaxf(mst[i], rmax[i]);
                const float alpha = EXP2F(mst[i] - mnew);
                mst[i] = mnew;
                lst[i] *= alpha;
#pragma unroll
                for (int jn = 0; jn < 8; ++jn)
#pragma unroll
                    for (int r = 0; r < 4; ++r) oacc[i][jn][r] *= alpha;
            }
        }

        float rsum[2] = {0.f, 0.f};
#pragma unroll
        for (int j = 0; j < 4; ++j)
#pragma unroll
            for (int i = 0; i < 2; ++i)
#pragma unroll
                for (int r = 0; r < 4; ++r) {
                    const float p = EXP2F(sT[j][i][r] - mst[i]);
                    sT[j][i][r] = p;
                    rsum[i] += p;
                }
#pragma unroll
        for (int i = 0; i < 2; ++i) {
            rsum[i] += __shfl_xor(rsum[i], 16, 64);
            rsum[i] += __shfl_xor(rsum[i], 32, 64);
            lst[i] += rsum[i];
        }

        // ---- all waves done reading KC/KR; P may now alias the KC region
        __syncthreads();

        // ---- write P strip: [row=16i+lr][col 8-blocks XOR row&7], stride 64
        u16* pw = KV_s + w * 2048;
#pragma unroll
        for (int i = 0; i < 2; ++i)
#pragma unroll
            for (int j = 0; j < 4; ++j) {
                const int row = 16 * i + lr;
                const int c8 = (2 * j + (lq >> 1)) ^ (row & 7);
                const u32 d0 = pk2(sT[j][i][0], sT[j][i][1]);
                const u32 d1 = pk2(sT[j][i][2], sT[j][i][3]);
                *(uint2*)(pw + row * 64 + c8 * 8 + 4 * (lq & 1)) = make_uint2(d0, d1);
            }

        // ---- O^T += V^T P^T: mfma(V-frag, P-frag)
#pragma unroll
        for (int kc = 0; kc < 2; ++kc) {
            short8 ap[2];
#pragma unroll
            for (int i = 0; i < 2; ++i) {
                const int row = 16 * i + lr;
                ap[i] = *(const short8*)(pw + row * 64 + (((4 * kc + lq) ^ (row & 7)) << 3));
            }
            __builtin_amdgcn_s_setprio(1);
#pragma unroll
            for (int jn = 0; jn < 8; ++jn) {
                const int drow = 16 * jn + lr;
                const int cc = (4 * kc + lq) ^ (drow & 7);
                const short8 bv = *(const short8*)(VT_s + drow * 64 + cc * 8);
#pragma unroll
                for (int i = 0; i < 2; ++i)
                    oacc[i][jn] = __builtin_amdgcn_mfma_f32_16x16x32_bf16(
                        bv, ap[i], oacc[i][jn], 0, 0, 0);
            }
            __builtin_amdgcn_s_setprio(0);
        }
        __syncthreads();
    }

    // ---- epilogue: O^T / l -> bf16, 8B packed stores (4 consecutive d)
#pragma unroll
    for (int i = 0; i < 2; ++i) {
        const float rl = 1.0f / lst[i];
        const long row = (long)b * 2048 + mbase + 16 * i + lr;
#pragma unroll
        for (int jn = 0; jn < 8; ++jn) {
            const u32 lo = pk2(oacc[i][jn][0] * rl, oacc[i][jn][1] * rl);
            const u32 hi = pk2(oacc[i][jn][2] * rl, oacc[i][jn][3] * rl);
            u16* dst = Obuf + row * 2048 + h * 128 + 16 * jn + 4 * lq;
            *(uint2*)dst = make_uint2(lo, hi);
        }
    }
}

// ---------------------------------------------------------------- launch
extern "C" void kernel_launch(void* const* d_in, const int* in_sizes, int n_in,
                              void* d_out, int out_size, void* d_ws, size_t ws_size,
                              hipStream_t stream)
{
    (void)in_sizes; (void)n_in; (void)out_size; (void)ws_size;

    u16* p = (u16*)d_ws;
    u16* qbf   = p; p += 8388608;
    u16* kvbf  = p; p += 8388608;
    u16* wqall = p; p += 6291456;   // rows 0..2047 = W_QC, 2048..3071 = W_QR
    u16* wkvall= p; p += 10485760;  // rows 0..2047 = W_KC, 2048..3071 = W_KR, 3072..5119 = W_V
    u16* wob   = p; p += 4194304;
    u16* QCb   = p; p += 8388608;
    u16* QRb   = p; p += 4194304;
    u16* KCb   = p; p += 8388608;
    u16* KRb   = p; p += 4194304;
    u16* VTb   = p; p += 8388608;
    u16* Ob    = p; p += 8388608;

    CastArgs a;
    a.src[0] = (const float*)d_in[0]; a.dst[0] = qbf;               a.scale[0] = QSCALE;
    a.src[1] = (const float*)d_in[1]; a.dst[1] = kvbf;              a.scale[1] = 1.f;
    a.src[2] = (const float*)d_in[2]; a.dst[2] = wqall;             a.scale[2] = 1.f;
    a.src[3] = (const float*)d_in[3]; a.dst[3] = wkvall;            a.scale[3] = 1.f;
    a.src[4] = (const float*)d_in[4]; a.dst[4] = wqall + 4194304;   a.scale[4] = 1.f;
    a.src[5] = (const float*)d_in[5]; a.dst[5] = wkvall + 4194304;  a.scale[5] = 1.f;
    a.src[6] = (const float*)d_in[6]; a.dst[6] = wkvall + 6291456;  a.scale[6] = 1.f;
    a.src[7] = (const float*)d_in[7]; a.dst[7] = wob;               a.scale[7] = 1.f;
    const int blks[8] = {8192, 8192, 4096, 4096, 2048, 2048, 4096, 4096};
    int acc = 0;
    for (int i = 0; i < 8; ++i) { a.startblk[i] = acc; acc += blks[i]; }

    cast_all_k<<<acc, 256, 0, stream>>>(a);

    // 1D grids (nbm=32 hardcoded in kernel): nwg = 32 * (N/128)
    gemm_bt<0><<<32 * 24, 256, 0, stream>>>(qbf,  wqall,  QCb, QRb, nullptr, 2048);
    gemm_bt<1><<<32 * 40, 256, 0, stream>>>(kvbf, wkvall, KCb, KRb, VTb,     2048);

    flash_attn<<<dim3(16, 16, 2), 256, 0, stream>>>(QCb, QRb, KCb, KRb, VTb, Ob);

    gemm_bt<2><<<32 * 16, 256, 0, stream>>>(Ob, wob, d_out, nullptr, nullptr, 2048);
}

// Round 7
// 485.116 us; speedup vs baseline: 1.6152x; 1.6152x over previous
//
#include <hip/hip_runtime.h>
#include <hip/hip_bf16.h>

typedef unsigned short u16;
typedef unsigned int u32;
typedef unsigned long long u64;
typedef __attribute__((ext_vector_type(8))) short short8;
typedef __attribute__((ext_vector_type(4))) float floatx4;

#if __has_builtin(__builtin_amdgcn_exp2f)
#define EXP2F(x) __builtin_amdgcn_exp2f(x)
#else
#define EXP2F(x) exp2f(x)
#endif

// SCALE * log2(e): softmax runs in base 2, scale pre-folded into Q cast.
#define QSCALE (0.07216878364870323f * 1.4426950408889634f)
#define ROPE_C 0.62286151779f   /* log2(1e6)/32 */

__device__ __forceinline__ u16 f2b(float f) {
    unsigned int x = __builtin_bit_cast(unsigned int, f);
    unsigned int r = (x + 0x7fffu + ((x >> 16) & 1u)) >> 16;   // RNE
    return (u16)r;
}
__device__ __forceinline__ u32 pk2(float a, float b) {
    return (u32)f2b(a) | ((u32)f2b(b) << 16);   // low 16 = a, high 16 = b
}
__device__ __forceinline__ void async16(const void* g, void* l) {
    __builtin_amdgcn_global_load_lds(
        (const __attribute__((address_space(1))) void*)g,
        (__attribute__((address_space(3))) void*)l, 16, 0, 0);
}

// ---------------------------------------------------------------- fused cast
struct CastArgs {
    const float* src[8];
    u16* dst[8];
    float scale[8];
    int startblk[8];
};

__global__ void cast_all_k(CastArgs a)
{
    const int bid = blockIdx.x;
    int s = 0;
#pragma unroll
    for (int i = 1; i < 8; ++i) s += (bid >= a.startblk[i]);
    const long idx = ((long)(bid - a.startblk[s]) * 256 + threadIdx.x) * 4;
    const float4 v = *(const float4*)(a.src[s] + idx);
    const float sc = a.scale[s];
    const u64 pk = (u64)pk2(v.x * sc, v.y * sc)
                 | ((u64)pk2(v.z * sc, v.w * sc) << 32);
    *(u64*)(a.dst[s] + idx) = pk;
}

// ---------------------------------------------------------------- GEMM  C = A(MxK) * B(NxK)^T
// Proven 128x128 / 256-thread / 3-blocks-per-CU structure, T1 bijective XCD
// swizzle (1D grid, wid = (id%8)*(nwg/8)+id/8, m-fastest within XCD chunk).
// EPI 0 (Q merged, N=3072): col<2048 -> QC bf16 (ld 2048); col>=2048 -> RoPE -> QR (ld 1024)
// EPI 1 (KV merged, N=5120): col<2048 -> KC; 2048..3071 -> RoPE -> KR; >=3072 -> V transposed (b,hd,n)
// EPI 2 (final, N=2048): f32 row-major
template<int EPI>
__global__ void __launch_bounds__(256, 3)
gemm_bt(const u16* __restrict__ A, const u16* __restrict__ Bw,
        void* __restrict__ out0, u16* __restrict__ out1, u16* __restrict__ out2,
        int K)
{
    __shared__ u16 As[128 * 64];
    __shared__ u16 Bs[128 * 64];
    const int t = threadIdx.x;
    const int w = t >> 6;
    const int lane = t & 63;
    const int lq = lane >> 4, lr = lane & 15;

    // bijective XCD swizzle (all grids are multiples of 8); nbm = 32 (M=4096)
    const int nwg = gridDim.x;
    const int id = blockIdx.x;
    const int wid = (id & 7) * (nwg >> 3) + (id >> 3);
    const long tileM = (long)(wid & 31) << 7;
    const long tileN = (long)(wid >> 5) << 7;

    const int wm = (w >> 1) * 64, wn = (w & 1) * 64;

    const floatx4 fzero = {0.f, 0.f, 0.f, 0.f};
    floatx4 acc[4][4];
#pragma unroll
    for (int i = 0; i < 4; ++i)
#pragma unroll
        for (int j = 0; j < 4; ++j) acc[i][j] = fzero;

    for (int k0 = 0; k0 < K; k0 += 64) {
#pragma unroll
        for (int r = 0; r < 4; ++r) {
            const int c = r * 256 + t;
            const int row = c >> 3, cc = c & 7;
            const int gcol = ((cc ^ (row & 7)) << 3);
            async16(A + (tileM + row) * (long)K + k0 + gcol, (char*)As + c * 16);
        }
#pragma unroll
        for (int r = 0; r < 4; ++r) {
            const int c = r * 256 + t;
            const int row = c >> 3, cc = c & 7;
            const int gcol = ((cc ^ (row & 7)) << 3);
            async16(Bw + (tileN + row) * (long)K + k0 + gcol, (char*)Bs + c * 16);
        }
        __builtin_amdgcn_s_waitcnt(0);
        __syncthreads();
#pragma unroll
        for (int kk = 0; kk < 2; ++kk) {
            short8 af[4], bfr[4];
#pragma unroll
            for (int i = 0; i < 4; ++i) {
                const int row = wm + 16 * i + lr;
                const int cc = (kk * 4 + lq) ^ (row & 7);
                af[i] = *(const short8*)(As + row * 64 + cc * 8);
            }
#pragma unroll
            for (int j = 0; j < 4; ++j) {
                const int row = wn + 16 * j + lr;
                const int cc = (kk * 4 + lq) ^ (row & 7);
                bfr[j] = *(const short8*)(Bs + row * 64 + cc * 8);
            }
            __builtin_amdgcn_s_setprio(1);
#pragma unroll
            for (int i = 0; i < 4; ++i)
#pragma unroll
                for (int j = 0; j < 4; ++j)
                    acc[i][j] = __builtin_amdgcn_mfma_f32_16x16x32_bf16(
                        af[i], bfr[j], acc[i][j], 0, 0, 0);
            __builtin_amdgcn_s_setprio(0);
        }
        __syncthreads();
    }

    // ---- epilogue (region is block-uniform: boundaries are multiples of 128)
    const bool isV    = (EPI == 1) && (tileN >= 3072);
    const bool isRope = (EPI != 2) && !isV && (tileN >= 2048);

#pragma unroll
    for (int i = 0; i < 4; ++i) {
#pragma unroll
        for (int j = 0; j < 4; ++j) {
            const long row0 = tileM + wm + 16 * i + 4 * lq;
            const long col  = tileN + wn + 16 * j + lr;
            if (EPI == 2) {
#pragma unroll
                for (int r = 0; r < 4; ++r)
                    ((float*)out0)[(row0 + r) * 2048 + col] = acc[i][j][r];
            } else if (isV) {
                const u32 lo = pk2(acc[i][j][0], acc[i][j][1]);
                const u32 hi = pk2(acc[i][j][2], acc[i][j][3]);
                const long bb = row0 >> 11;
                u16* dst = out2 + ((bb * 2048 + (col - 3072)) << 11) + (row0 & 2047);
                *(uint2*)dst = make_uint2(lo, hi);
            } else if (isRope) {
                const int jj = ((int)col & 63) >> 1;
                const float freq = EXP2F(-ROPE_C * (float)jj);
#pragma unroll
                for (int r = 0; r < 4; ++r) {
                    const float v = acc[i][j][r];
                    const float vp = __shfl_xor(v, 1, 64);
                    const long row = row0 + r;
                    float sn, cs;
                    __sincosf((float)(row & 2047) * freq, &sn, &cs);
                    const float o = (col & 1) ? (v * cs + vp * sn) : (v * cs - vp * sn);
                    out1[row * 1024 + (col - 2048)] = f2b(o);
                }
            } else {
#pragma unroll
                for (int r = 0; r < 4; ++r)
                    ((u16*)out0)[(row0 + r) * 2048 + col] = f2b(acc[i][j][r]);
            }
        }
    }
}

// ---------------------------------------------------------------- flash attention (S^T dataflow)
// grid (16, 16, 2), 256 threads (4 waves), wave owns a 32-row Q strip.
// XCD remap: h = 2*(x&7) + (y&1), qx = 8*(x>>3) + (y>>1) (bijective) — all 16
// Q-tiles of a head on one XCD so its K/V panels stay in that XCD's L2.
// launch_bounds(256,2): kernel needs ~184 unified regs (120 arch + 64 acc);
// forcing 4 blocks/CU (round-4) spilled the accumulator -> 839MB scratch
// fetch, 3.5x slowdown. 2 blocks/CU is the register-feasible occupancy.
// LDS 40960 B; P aliases the KC region (KC/KR live only in QK^T phase,
// P only in PV; one __syncthreads between). P layout: stride 64 + 8-block
// XOR row&7 — same scheme as the K/V reads which measure 0 conflicts.
__global__ void __launch_bounds__(256, 2)
flash_attn(const u16* __restrict__ QC, const u16* __restrict__ QR,
           const u16* __restrict__ KC, const u16* __restrict__ KR,
           const u16* __restrict__ VT, u16* __restrict__ Obuf)
{
    __shared__ u16 KV_s[64 * 128 + 64 * 64];  // KC @0 (16KB), KR @8192 elem (8KB); P aliases KC
    __shared__ u16 VT_s[128 * 64];            // 16KB

    const int t = threadIdx.x;
    const int w = t >> 6;
    const int lane = t & 63;
    const int lq = lane >> 4, lr = lane & 15;
    const int bx = blockIdx.x, by = blockIdx.y;
    const int h  = ((bx & 7) << 1) | (by & 1);     // head: fixed x&7 -> fixed XCD
    const int qx = ((bx >> 3) << 3) | (by >> 1);   // Q tile index 0..15
    const int mbase = qx * 128 + w * 32;
    const int b = blockIdx.z;

    // Q fragments (Y-operand layout [m=lane&15][k=lq*8+j]) in registers
    short8 aq[2][6];
#pragma unroll
    for (int i = 0; i < 2; ++i) {
        const long m = mbase + 16 * i + lr;
        const u16* qc = QC + ((long)b * 2048 + m) * 2048 + h * 128;
        const u16* qr = QR + ((long)b * 2048 + m) * 1024 + h * 64;
#pragma unroll
        for (int kc = 0; kc < 4; ++kc) aq[i][kc]     = *(const short8*)(qc + kc * 32 + lq * 8);
#pragma unroll
        for (int kc = 0; kc < 2; ++kc) aq[i][4 + kc] = *(const short8*)(qr + kc * 32 + lq * 8);
    }

    const floatx4 fzero = {0.f, 0.f, 0.f, 0.f};
    float mst[2], lst[2];
    floatx4 oacc[2][8];   // O^T: rows d (tile jn, 4lq+r), cols m = lr (strip i)
#pragma unroll
    for (int i = 0; i < 2; ++i) {
        mst[i] = -1e30f; lst[i] = 0.f;
#pragma unroll
        for (int jn = 0; jn < 8; ++jn) oacc[i][jn] = fzero;
    }

    const u16* kc_g = KC + ((long)b * 2048) * 2048 + h * 128;
    const u16* kr_g = KR + ((long)b * 2048) * 1024 + h * 64;
    const u16* vt_g = VT + ((long)(b * 16 + h) * 128) * 2048;

    for (int kt = 0; kt < 32; ++kt) {
#pragma unroll
        for (int r = 0; r < 4; ++r) {
            const int c = r * 256 + t;
            const int krow = c >> 4, cc = c & 15;
            const int gc = cc ^ (krow & 7);
            async16(kc_g + (long)(kt * 64 + krow) * 2048 + gc * 8, (char*)KV_s + c * 16);
        }
#pragma unroll
        for (int r = 0; r < 2; ++r) {
            const int c = r * 256 + t;
            const int krow = c >> 3, cc = c & 7;
            const int gc = cc ^ (krow & 7);
            async16(kr_g + (long)(kt * 64 + krow) * 1024 + gc * 8, (char*)KV_s + 16384 + c * 16);
        }
#pragma unroll
        for (int r = 0; r < 4; ++r) {
            const int c = r * 256 + t;
            const int drow = c >> 3, cc = c & 7;
            const int gc = cc ^ (drow & 7);
            async16(vt_g + (long)drow * 2048 + kt * 64 + gc * 8, (char*)VT_s + c * 16);
        }
        __builtin_amdgcn_s_waitcnt(0);
        __syncthreads();

        // ---- S^T = K Q^T: sT[j][i] rows n (16j+4lq+r), cols m (16i, lane lr)
        floatx4 sT[4][2];
#pragma unroll
        for (int j = 0; j < 4; ++j)
#pragma unroll
            for (int i = 0; i < 2; ++i) sT[j][i] = fzero;
#pragma unroll
        for (int kc = 0; kc < 6; ++kc) {
            short8 kf[4];
#pragma unroll
            for (int j = 0; j < 4; ++j) {
                const int krow = 16 * j + lr;
                if (kc < 4) {
                    const int cc = (4 * kc + lq) ^ (krow & 7);
                    kf[j] = *(const short8*)(KV_s + krow * 128 + cc * 8);
                } else {
                    const int cc = (4 * (kc - 4) + lq) ^ (krow & 7);
                    kf[j] = *(const short8*)(KV_s + 8192 + krow * 64 + cc * 8);
                }
            }
            __builtin_amdgcn_s_setprio(1);
#pragma unroll
            for (int j = 0; j < 4; ++j)
#pragma unroll
                for (int i = 0; i < 2; ++i)
                    sT[j][i] = __builtin_amdgcn_mfma_f32_16x16x32_bf16(
                        kf[j], aq[i][kc], sT[j][i], 0, 0, 0);
            __builtin_amdgcn_s_setprio(0);
        }

        // ---- online softmax: per-lane over 16 regs, then 2 shuffle rounds (lq groups)
        float rmax[2];
#pragma unroll
        for (int i = 0; i < 2; ++i) {
            float a0 = fmaxf(fmaxf(sT[0][i][0], sT[0][i][1]), fmaxf(sT[0][i][2], sT[0][i][3]));
            float a1 = fmaxf(fmaxf(sT[1][i][0], sT[1][i][1]), fmaxf(sT[1][i][2], sT[1][i][3]));
            float a2 = fmaxf(fmaxf(sT[2][i][0], sT[2][i][1]), fmaxf(sT[2][i][2], sT[2][i][3]));
            float a3 = fmaxf(fmaxf(sT[3][i][0], sT[3][i][1]), fmaxf(sT[3][i][2], sT[3][i][3]));
            rmax[i] = fmaxf(fmaxf(a0, a1), fmaxf(a2, a3));
        }
#pragma unroll
        for (int i = 0; i < 2; ++i) {
            rmax[i] = fmaxf(rmax[i], __shfl_xor(rmax[i], 16, 64));
            rmax[i] = fmaxf(rmax[i], __shfl_xor(rmax[i], 32, 64));
        }

        // T13 defer-max: only rescale when max grew by >8 (P bounded by 2^8, bf16-safe)
        const int upd = (rmax[0] > mst[0] + 8.f) | (rmax[1] > mst[1] + 8.f);
        if (__any(upd)) {
#pragma unroll
            for (int i = 0; i < 2; ++i) {
                const float mnew = fmaxf(mst[i], rmax[i]);
                const float alpha = EXP2F(mst[i] - mnew);
                mst[i] = mnew;
                lst[i] *= alpha;
#pragma unroll
                for (int jn = 0; jn < 8; ++jn)
#pragma unroll
                    for (int r = 0; r < 4; ++r) oacc[i][jn][r] *= alpha;
            }
        }

        float rsum[2] = {0.f, 0.f};
#pragma unroll
        for (int j = 0; j < 4; ++j)
#pragma unroll
            for (int i = 0; i < 2; ++i)
#pragma unroll
                for (int r = 0; r < 4; ++r) {
                    const float p = EXP2F(sT[j][i][r] - mst[i]);
                    sT[j][i][r] = p;
                    rsum[i] += p;
                }
#pragma unroll
        for (int i = 0; i < 2; ++i) {
            rsum[i] += __shfl_xor(rsum[i], 16, 64);
            rsum[i] += __shfl_xor(rsum[i], 32, 64);
            lst[i] += rsum[i];
        }

        // ---- all waves done reading KC/KR; P may now alias the KC region
        __syncthreads();

        // ---- write P strip: [row=16i+lr][col 8-blocks XOR row&7], stride 64
        u16* pw = KV_s + w * 2048;
#pragma unroll
        for (int i = 0; i < 2; ++i)
#pragma unroll
            for (int j = 0; j < 4; ++j) {
                const int row = 16 * i + lr;
                const int c8 = (2 * j + (lq >> 1)) ^ (row & 7);
                const u32 d0 = pk2(sT[j][i][0], sT[j][i][1]);
                const u32 d1 = pk2(sT[j][i][2], sT[j][i][3]);
                *(uint2*)(pw + row * 64 + c8 * 8 + 4 * (lq & 1)) = make_uint2(d0, d1);
            }

        // ---- O^T += V^T P^T: mfma(V-frag, P-frag)
#pragma unroll
        for (int kc = 0; kc < 2; ++kc) {
            short8 ap[2];
#pragma unroll
            for (int i = 0; i < 2; ++i) {
                const int row = 16 * i + lr;
                ap[i] = *(const short8*)(pw + row * 64 + (((4 * kc + lq) ^ (row & 7)) << 3));
            }
            __builtin_amdgcn_s_setprio(1);
#pragma unroll
            for (int jn = 0; jn < 8; ++jn) {
                const int drow = 16 * jn + lr;
                const int cc = (4 * kc + lq) ^ (drow & 7);
                const short8 bv = *(const short8*)(VT_s + drow * 64 + cc * 8);
#pragma unroll
                for (int i = 0; i < 2; ++i)
                    oacc[i][jn] = __builtin_amdgcn_mfma_f32_16x16x32_bf16(
                        bv, ap[i], oacc[i][jn], 0, 0, 0);
            }
            __builtin_amdgcn_s_setprio(0);
        }
        __syncthreads();
    }

    // ---- epilogue: O^T / l -> bf16, 8B packed stores (4 consecutive d)
#pragma unroll
    for (int i = 0; i < 2; ++i) {
        const float rl = 1.0f / lst[i];
        const long row = (long)b * 2048 + mbase + 16 * i + lr;
#pragma unroll
        for (int jn = 0; jn < 8; ++jn) {
            const u32 lo = pk2(oacc[i][jn][0] * rl, oacc[i][jn][1] * rl);
            const u32 hi = pk2(oacc[i][jn][2] * rl, oacc[i][jn][3] * rl);
            u16* dst = Obuf + row * 2048 + h * 128 + 16 * jn + 4 * lq;
            *(uint2*)dst = make_uint2(lo, hi);
        }
    }
}

// ---------------------------------------------------------------- launch
extern "C" void kernel_launch(void* const* d_in, const int* in_sizes, int n_in,
                              void* d_out, int out_size, void* d_ws, size_t ws_size,
                              hipStream_t stream)
{
    (void)in_sizes; (void)n_in; (void)out_size; (void)ws_size;

    u16* p = (u16*)d_ws;
    u16* qbf   = p; p += 8388608;
    u16* kvbf  = p; p += 8388608;
    u16* wqall = p; p += 6291456;   // rows 0..2047 = W_QC, 2048..3071 = W_QR
    u16* wkvall= p; p += 10485760;  // rows 0..2047 = W_KC, 2048..3071 = W_KR, 3072..5119 = W_V
    u16* wob   = p; p += 4194304;
    u16* QCb   = p; p += 8388608;
    u16* QRb   = p; p += 4194304;
    u16* KCb   = p; p += 8388608;
    u16* KRb   = p; p += 4194304;
    u16* VTb   = p; p += 8388608;
    u16* Ob    = p; p += 8388608;

    CastArgs a;
    a.src[0] = (const float*)d_in[0]; a.dst[0] = qbf;               a.scale[0] = QSCALE;
    a.src[1] = (const float*)d_in[1]; a.dst[1] = kvbf;              a.scale[1] = 1.f;
    a.src[2] = (const float*)d_in[2]; a.dst[2] = wqall;             a.scale[2] = 1.f;
    a.src[3] = (const float*)d_in[3]; a.dst[3] = wkvall;            a.scale[3] = 1.f;
    a.src[4] = (const float*)d_in[4]; a.dst[4] = wqall + 4194304;   a.scale[4] = 1.f;
    a.src[5] = (const float*)d_in[5]; a.dst[5] = wkvall + 4194304;  a.scale[5] = 1.f;
    a.src[6] = (const float*)d_in[6]; a.dst[6] = wkvall + 6291456;  a.scale[6] = 1.f;
    a.src[7] = (const float*)d_in[7]; a.dst[7] = wob;               a.scale[7] = 1.f;
    const int blks[8] = {8192, 8192, 4096, 4096, 2048, 2048, 4096, 4096};
    int acc = 0;
    for (int i = 0; i < 8; ++i) { a.startblk[i] = acc; acc += blks[i]; }

    cast_all_k<<<acc, 256, 0, stream>>>(a);

    // 1D grids (nbm=32 hardcoded in kernel): nwg = 32 * (N/128)
    gemm_bt<0><<<32 * 24, 256, 0, stream>>>(qbf,  wqall,  QCb, QRb, nullptr, 2048);
    gemm_bt<1><<<32 * 40, 256, 0, stream>>>(kvbf, wkvall, KCb, KRb, VTb,     2048);

    flash_attn<<<dim3(16, 16, 2), 256, 0, stream>>>(QCb, QRb, KCb, KRb, VTb, Ob);

    gemm_bt<2><<<32 * 16, 256, 0, stream>>>(Ob, wob, d_out, nullptr, nullptr, 2048);
}

// Round 8
// 481.165 us; speedup vs baseline: 1.6285x; 1.0082x over previous
//
#include <hip/hip_runtime.h>
#include <hip/hip_bf16.h>

typedef unsigned short u16;
typedef unsigned int u32;
typedef unsigned long long u64;
typedef __attribute__((ext_vector_type(8))) short short8;
typedef __attribute__((ext_vector_type(4))) float floatx4;

#if __has_builtin(__builtin_amdgcn_exp2f)
#define EXP2F(x) __builtin_amdgcn_exp2f(x)
#else
#define EXP2F(x) exp2f(x)
#endif

// SCALE * log2(e): softmax runs in base 2, scale pre-folded into Q cast.
#define QSCALE (0.07216878364870323f * 1.4426950408889634f)
#define ROPE_C 0.62286151779f   /* log2(1e6)/32 */

__device__ __forceinline__ u16 f2b(float f) {
    unsigned int x = __builtin_bit_cast(unsigned int, f);
    unsigned int r = (x + 0x7fffu + ((x >> 16) & 1u)) >> 16;   // RNE
    return (u16)r;
}
__device__ __forceinline__ u32 pk2(float a, float b) {
    return (u32)f2b(a) | ((u32)f2b(b) << 16);   // low 16 = a, high 16 = b
}
__device__ __forceinline__ void async16(const void* g, void* l) {
    __builtin_amdgcn_global_load_lds(
        (const __attribute__((address_space(1))) void*)g,
        (__attribute__((address_space(3))) void*)l, 16, 0, 0);
}

// ---------------------------------------------------------------- fused cast
struct CastArgs {
    const float* src[8];
    u16* dst[8];
    float scale[8];
    int startblk[8];
};

__global__ void cast_all_k(CastArgs a)
{
    const int bid = blockIdx.x;
    int s = 0;
#pragma unroll
    for (int i = 1; i < 8; ++i) s += (bid >= a.startblk[i]);
    const long idx = ((long)(bid - a.startblk[s]) * 256 + threadIdx.x) * 4;
    const float4 v = *(const float4*)(a.src[s] + idx);
    const float sc = a.scale[s];
    const u64 pk = (u64)pk2(v.x * sc, v.y * sc)
                 | ((u64)pk2(v.z * sc, v.w * sc) << 32);
    *(u64*)(a.dst[s] + idx) = pk;
}

// ---------------------------------------------------------------- GEMM  C = A(MxK) * B(NxK)^T
// Proven 128x128 / 256-thread / 3-blocks-per-CU structure, T1 bijective XCD
// swizzle (1D grid, wid = (id%8)*(nwg/8)+id/8, m-fastest within XCD chunk).
// EPI 0 (Q merged, N=3072): col<2048 -> QC bf16 (ld 2048); col>=2048 -> RoPE -> QR (ld 1024)
// EPI 1 (KV merged, N=5120): col<2048 -> KC; 2048..3071 -> RoPE -> KR; >=3072 -> V transposed (b,hd,n)
// EPI 2 (final, N=2048): f32 row-major
template<int EPI>
__global__ void __launch_bounds__(256, 3)
gemm_bt(const u16* __restrict__ A, const u16* __restrict__ Bw,
        void* __restrict__ out0, u16* __restrict__ out1, u16* __restrict__ out2,
        int K)
{
    __shared__ u16 As[128 * 64];
    __shared__ u16 Bs[128 * 64];
    const int t = threadIdx.x;
    const int w = t >> 6;
    const int lane = t & 63;
    const int lq = lane >> 4, lr = lane & 15;

    // bijective XCD swizzle (all grids are multiples of 8); nbm = 32 (M=4096)
    const int nwg = gridDim.x;
    const int id = blockIdx.x;
    const int wid = (id & 7) * (nwg >> 3) + (id >> 3);
    const long tileM = (long)(wid & 31) << 7;
    const long tileN = (long)(wid >> 5) << 7;

    const int wm = (w >> 1) * 64, wn = (w & 1) * 64;

    const floatx4 fzero = {0.f, 0.f, 0.f, 0.f};
    floatx4 acc[4][4];
#pragma unroll
    for (int i = 0; i < 4; ++i)
#pragma unroll
        for (int j = 0; j < 4; ++j) acc[i][j] = fzero;

    for (int k0 = 0; k0 < K; k0 += 64) {
#pragma unroll
        for (int r = 0; r < 4; ++r) {
            const int c = r * 256 + t;
            const int row = c >> 3, cc = c & 7;
            const int gcol = ((cc ^ (row & 7)) << 3);
            async16(A + (tileM + row) * (long)K + k0 + gcol, (char*)As + c * 16);
        }
#pragma unroll
        for (int r = 0; r < 4; ++r) {
            const int c = r * 256 + t;
            const int row = c >> 3, cc = c & 7;
            const int gcol = ((cc ^ (row & 7)) << 3);
            async16(Bw + (tileN + row) * (long)K + k0 + gcol, (char*)Bs + c * 16);
        }
        __builtin_amdgcn_s_waitcnt(0);
        __syncthreads();
#pragma unroll
        for (int kk = 0; kk < 2; ++kk) {
            short8 af[4], bfr[4];
#pragma unroll
            for (int i = 0; i < 4; ++i) {
                const int row = wm + 16 * i + lr;
                const int cc = (kk * 4 + lq) ^ (row & 7);
                af[i] = *(const short8*)(As + row * 64 + cc * 8);
            }
#pragma unroll
            for (int j = 0; j < 4; ++j) {
                const int row = wn + 16 * j + lr;
                const int cc = (kk * 4 + lq) ^ (row & 7);
                bfr[j] = *(const short8*)(Bs + row * 64 + cc * 8);
            }
            __builtin_amdgcn_s_setprio(1);
#pragma unroll
            for (int i = 0; i < 4; ++i)
#pragma unroll
                for (int j = 0; j < 4; ++j)
                    acc[i][j] = __builtin_amdgcn_mfma_f32_16x16x32_bf16(
                        af[i], bfr[j], acc[i][j], 0, 0, 0);
            __builtin_amdgcn_s_setprio(0);
        }
        __syncthreads();
    }

    // ---- epilogue (region is block-uniform: boundaries are multiples of 128)
    const bool isV    = (EPI == 1) && (tileN >= 3072);
    const bool isRope = (EPI != 2) && !isV && (tileN >= 2048);

#pragma unroll
    for (int i = 0; i < 4; ++i) {
#pragma unroll
        for (int j = 0; j < 4; ++j) {
            const long row0 = tileM + wm + 16 * i + 4 * lq;
            const long col  = tileN + wn + 16 * j + lr;
            if (EPI == 2) {
#pragma unroll
                for (int r = 0; r < 4; ++r)
                    ((float*)out0)[(row0 + r) * 2048 + col] = acc[i][j][r];
            } else if (isV) {
                const u32 lo = pk2(acc[i][j][0], acc[i][j][1]);
                const u32 hi = pk2(acc[i][j][2], acc[i][j][3]);
                const long bb = row0 >> 11;
                u16* dst = out2 + ((bb * 2048 + (col - 3072)) << 11) + (row0 & 2047);
                *(uint2*)dst = make_uint2(lo, hi);
            } else if (isRope) {
                const int jj = ((int)col & 63) >> 1;
                const float freq = EXP2F(-ROPE_C * (float)jj);
#pragma unroll
                for (int r = 0; r < 4; ++r) {
                    const float v = acc[i][j][r];
                    const float vp = __shfl_xor(v, 1, 64);
                    const long row = row0 + r;
                    float sn, cs;
                    __sincosf((float)(row & 2047) * freq, &sn, &cs);
                    const float o = (col & 1) ? (v * cs + vp * sn) : (v * cs - vp * sn);
                    out1[row * 1024 + (col - 2048)] = f2b(o);
                }
            } else {
#pragma unroll
                for (int r = 0; r < 4; ++r)
                    ((u16*)out0)[(row0 + r) * 2048 + col] = f2b(acc[i][j][r]);
            }
        }
    }
}

// ---------------------------------------------------------------- flash attention (S^T dataflow)
// grid (16, 16, 2), 256 threads (4 waves), wave owns a 32-row Q strip.
// XCD remap: h = 2*(x&7) + (y&1), qx = 8*(x>>3) + (y>>1) (bijective).
// launch_bounds(256,2): needs ~184 unified regs (120 arch + 64 acc);
// forcing 4 blocks/CU spills the accumulator (round-4: 839MB scratch traffic).
// DOUBLE-BUFFERED staging (T3/T4): two 40KB buffers (81920 B total = exactly
// the 80KB/block budget at 2 blocks/CU). Issue tile kt+1's 10 global_load_lds
// into buf[cur^1], then s_waitcnt vmcnt(10) (waits tile kt only; kt+1 stays in
// flight across compute) + raw s_barrier. __syncthreads is NOT used in the
// loop: hipcc would emit a full vmcnt(0) drain before it, serializing staging.
// Buffer layout (u16 elems): KC @0 (8192), KR @8192 (4096), VT @12288 (8192).
// P (wave-private, 2048/wave) aliases the KC region after the mid-barrier.
// Invariants: stage into buf[x] only ever issued >=1 full barrier after the
// last read of buf[x]; P overwrites buf[cur].KC only after all waves' QK^T
// reads (mid-barrier); next stage into buf[cur] issued after end-barrier.
__global__ void __launch_bounds__(256, 2)
flash_attn(const u16* __restrict__ QC, const u16* __restrict__ QR,
           const u16* __restrict__ KC, const u16* __restrict__ KR,
           const u16* __restrict__ VT, u16* __restrict__ Obuf)
{
    __shared__ u16 BUF[2][20480];   // 2 x 40KB

    const int t = threadIdx.x;
    const int w = t >> 6;
    const int lane = t & 63;
    const int lq = lane >> 4, lr = lane & 15;
    const int bx = blockIdx.x, by = blockIdx.y;
    const int h  = ((bx & 7) << 1) | (by & 1);     // head: fixed x&7 -> fixed XCD
    const int qx = ((bx >> 3) << 3) | (by >> 1);   // Q tile index 0..15
    const int mbase = qx * 128 + w * 32;
    const int b = blockIdx.z;

    // Q fragments (Y-operand layout [m=lane&15][k=lq*8+j]) in registers
    short8 aq[2][6];
#pragma unroll
    for (int i = 0; i < 2; ++i) {
        const long m = mbase + 16 * i + lr;
        const u16* qc = QC + ((long)b * 2048 + m) * 2048 + h * 128;
        const u16* qr = QR + ((long)b * 2048 + m) * 1024 + h * 64;
#pragma unroll
        for (int kc = 0; kc < 4; ++kc) aq[i][kc]     = *(const short8*)(qc + kc * 32 + lq * 8);
#pragma unroll
        for (int kc = 0; kc < 2; ++kc) aq[i][4 + kc] = *(const short8*)(qr + kc * 32 + lq * 8);
    }

    const floatx4 fzero = {0.f, 0.f, 0.f, 0.f};
    float mst[2], lst[2];
    floatx4 oacc[2][8];   // O^T: rows d (tile jn, 4lq+r), cols m = lr (strip i)
#pragma unroll
    for (int i = 0; i < 2; ++i) {
        mst[i] = -1e30f; lst[i] = 0.f;
#pragma unroll
        for (int jn = 0; jn < 8; ++jn) oacc[i][jn] = fzero;
    }

    const u16* kc_g = KC + ((long)b * 2048) * 2048 + h * 128;
    const u16* kr_g = KR + ((long)b * 2048) * 1024 + h * 64;
    const u16* vt_g = VT + ((long)(b * 16 + h) * 128) * 2048;

    // stage tile kt (10 async16/thread) into buffer bf
    auto stage = [&](int bf, int kt) {
        char* base = (char*)&BUF[bf][0];
#pragma unroll
        for (int r = 0; r < 4; ++r) {
            const int c = r * 256 + t;
            const int krow = c >> 4, cc = c & 15;
            const int gc = cc ^ (krow & 7);
            async16(kc_g + (long)(kt * 64 + krow) * 2048 + gc * 8, base + c * 16);
        }
#pragma unroll
        for (int r = 0; r < 2; ++r) {
            const int c = r * 256 + t;
            const int krow = c >> 3, cc = c & 7;
            const int gc = cc ^ (krow & 7);
            async16(kr_g + (long)(kt * 64 + krow) * 1024 + gc * 8, base + 16384 + c * 16);
        }
#pragma unroll
        for (int r = 0; r < 4; ++r) {
            const int c = r * 256 + t;
            const int drow = c >> 3, cc = c & 7;
            const int gc = cc ^ (drow & 7);
            async16(vt_g + (long)drow * 2048 + kt * 64 + gc * 8, base + 24576 + c * 16);
        }
    };

    stage(0, 0);   // prologue

    for (int kt = 0; kt < 32; ++kt) {
        const int cur = kt & 1;
        if (kt + 1 < 32) stage(cur ^ 1, kt + 1);
        __builtin_amdgcn_sched_barrier(0);
        if (kt + 1 < 32) { asm volatile("s_waitcnt vmcnt(10)" ::: "memory"); }
        else             { asm volatile("s_waitcnt vmcnt(0)"  ::: "memory"); }
        __builtin_amdgcn_sched_barrier(0);
        __builtin_amdgcn_s_barrier();            // tile kt resident for all waves
        __builtin_amdgcn_sched_barrier(0);

        u16* kv = &BUF[cur][0];

        // ---- S^T = K Q^T: sT[j][i] rows n (16j+4lq+r), cols m (16i, lane lr)
        floatx4 sT[4][2];
#pragma unroll
        for (int j = 0; j < 4; ++j)
#pragma unroll
            for (int i = 0; i < 2; ++i) sT[j][i] = fzero;
#pragma unroll
        for (int kc = 0; kc < 6; ++kc) {
            short8 kf[4];
#pragma unroll
            for (int j = 0; j < 4; ++j) {
                const int krow = 16 * j + lr;
                if (kc < 4) {
                    const int cc = (4 * kc + lq) ^ (krow & 7);
                    kf[j] = *(const short8*)(kv + krow * 128 + cc * 8);
                } else {
                    const int cc = (4 * (kc - 4) + lq) ^ (krow & 7);
                    kf[j] = *(const short8*)(kv + 8192 + krow * 64 + cc * 8);
                }
            }
            __builtin_amdgcn_s_setprio(1);
#pragma unroll
            for (int j = 0; j < 4; ++j)
#pragma unroll
                for (int i = 0; i < 2; ++i)
                    sT[j][i] = __builtin_amdgcn_mfma_f32_16x16x32_bf16(
                        kf[j], aq[i][kc], sT[j][i], 0, 0, 0);
            __builtin_amdgcn_s_setprio(0);
        }

        // ---- online softmax: per-lane over 16 regs, then 2 shuffle rounds (lq groups)
        float rmax[2];
#pragma unroll
        for (int i = 0; i < 2; ++i) {
            float a0 = fmaxf(fmaxf(sT[0][i][0], sT[0][i][1]), fmaxf(sT[0][i][2], sT[0][i][3]));
            float a1 = fmaxf(fmaxf(sT[1][i][0], sT[1][i][1]), fmaxf(sT[1][i][2], sT[1][i][3]));
            float a2 = fmaxf(fmaxf(sT[2][i][0], sT[2][i][1]), fmaxf(sT[2][i][2], sT[2][i][3]));
            float a3 = fmaxf(fmaxf(sT[3][i][0], sT[3][i][1]), fmaxf(sT[3][i][2], sT[3][i][3]));
            rmax[i] = fmaxf(fmaxf(a0, a1), fmaxf(a2, a3));
        }
#pragma unroll
        for (int i = 0; i < 2; ++i) {
            rmax[i] = fmaxf(rmax[i], __shfl_xor(rmax[i], 16, 64));
            rmax[i] = fmaxf(rmax[i], __shfl_xor(rmax[i], 32, 64));
        }

        // T13 defer-max: only rescale when max grew by >8 (P bounded by 2^8, bf16-safe)
        const int upd = (rmax[0] > mst[0] + 8.f) | (rmax[1] > mst[1] + 8.f);
        if (__any(upd)) {
#pragma unroll
            for (int i = 0; i < 2; ++i) {
                const float mnew = fmaxf(mst[i], rmax[i]);
                const float alpha = EXP2F(mst[i] - mnew);
                mst[i] = mnew;
                lst[i] *= alpha;
#pragma unroll
                for (int jn = 0; jn < 8; ++jn)
#pragma unroll
                    for (int r = 0; r < 4; ++r) oacc[i][jn][r] *= alpha;
            }
        }

        float rsum[2] = {0.f, 0.f};
#pragma unroll
        for (int j = 0; j < 4; ++j)
#pragma unroll
            for (int i = 0; i < 2; ++i)
#pragma unroll
                for (int r = 0; r < 4; ++r) {
                    const float p = EXP2F(sT[j][i][r] - mst[i]);
                    sT[j][i][r] = p;
                    rsum[i] += p;
                }
#pragma unroll
        for (int i = 0; i < 2; ++i) {
            rsum[i] += __shfl_xor(rsum[i], 16, 64);
            rsum[i] += __shfl_xor(rsum[i], 32, 64);
            lst[i] += rsum[i];
        }

        // ---- all waves done reading KC/KR of buf[cur]; P may alias its KC region
        __builtin_amdgcn_sched_barrier(0);
        __builtin_amdgcn_s_barrier();
        __builtin_amdgcn_sched_barrier(0);

        // ---- write P strip: [row=16i+lr][col 8-blocks XOR row&7], stride 64
        u16* pw = kv + w * 2048;
#pragma unroll
        for (int i = 0; i < 2; ++i)
#pragma unroll
            for (int j = 0; j < 4; ++j) {
                const int row = 16 * i + lr;
                const int c8 = (2 * j + (lq >> 1)) ^ (row & 7);
                const u32 d0 = pk2(sT[j][i][0], sT[j][i][1]);
                const u32 d1 = pk2(sT[j][i][2], sT[j][i][3]);
                *(uint2*)(pw + row * 64 + c8 * 8 + 4 * (lq & 1)) = make_uint2(d0, d1);
            }

        // ---- O^T += V^T P^T: mfma(V-frag, P-frag)
#pragma unroll
        for (int kc = 0; kc < 2; ++kc) {
            short8 ap[2];
#pragma unroll
            for (int i = 0; i < 2; ++i) {
                const int row = 16 * i + lr;
                ap[i] = *(const short8*)(pw + row * 64 + (((4 * kc + lq) ^ (row & 7)) << 3));
            }
            __builtin_amdgcn_s_setprio(1);
#pragma unroll
            for (int jn = 0; jn < 8; ++jn) {
                const int drow = 16 * jn + lr;
                const int cc = (4 * kc + lq) ^ (drow & 7);
                const short8 bv = *(const short8*)(kv + 12288 + drow * 64 + cc * 8);
#pragma unroll
                for (int i = 0; i < 2; ++i)
                    oacc[i][jn] = __builtin_amdgcn_mfma_f32_16x16x32_bf16(
                        bv, ap[i], oacc[i][jn], 0, 0, 0);
            }
            __builtin_amdgcn_s_setprio(0);
        }

        // ---- all waves done with buf[cur]; next iteration may stage into it
        __builtin_amdgcn_sched_barrier(0);
        __builtin_amdgcn_s_barrier();
        __builtin_amdgcn_sched_barrier(0);
    }

    // ---- epilogue: O^T / l -> bf16, 8B packed stores (4 consecutive d)
#pragma unroll
    for (int i = 0; i < 2; ++i) {
        const float rl = 1.0f / lst[i];
        const long row = (long)b * 2048 + mbase + 16 * i + lr;
#pragma unroll
        for (int jn = 0; jn < 8; ++jn) {
            const u32 lo = pk2(oacc[i][jn][0] * rl, oacc[i][jn][1] * rl);
            const u32 hi = pk2(oacc[i][jn][2] * rl, oacc[i][jn][3] * rl);
            u16* dst = Obuf + row * 2048 + h * 128 + 16 * jn + 4 * lq;
            *(uint2*)dst = make_uint2(lo, hi);
        }
    }
}

// ---------------------------------------------------------------- launch
extern "C" void kernel_launch(void* const* d_in, const int* in_sizes, int n_in,
                              void* d_out, int out_size, void* d_ws, size_t ws_size,
                              hipStream_t stream)
{
    (void)in_sizes; (void)n_in; (void)out_size; (void)ws_size;

    u16* p = (u16*)d_ws;
    u16* qbf   = p; p += 8388608;
    u16* kvbf  = p; p += 8388608;
    u16* wqall = p; p += 6291456;   // rows 0..2047 = W_QC, 2048..3071 = W_QR
    u16* wkvall= p; p += 10485760;  // rows 0..2047 = W_KC, 2048..3071 = W_KR, 3072..5119 = W_V
    u16* wob   = p; p += 4194304;
    u16* QCb   = p; p += 8388608;
    u16* QRb   = p; p += 4194304;
    u16* KCb   = p; p += 8388608;
    u16* KRb   = p; p += 4194304;
    u16* VTb   = p; p += 8388608;
    u16* Ob    = p; p += 8388608;

    CastArgs a;
    a.src[0] = (const float*)d_in[0]; a.dst[0] = qbf;               a.scale[0] = QSCALE;
    a.src[1] = (const float*)d_in[1]; a.dst[1] = kvbf;              a.scale[1] = 1.f;
    a.src[2] = (const float*)d_in[2]; a.dst[2] = wqall;             a.scale[2] = 1.f;
    a.src[3] = (const float*)d_in[3]; a.dst[3] = wkvall;            a.scale[3] = 1.f;
    a.src[4] = (const float*)d_in[4]; a.dst[4] = wqall + 4194304;   a.scale[4] = 1.f;
    a.src[5] = (const float*)d_in[5]; a.dst[5] = wkvall + 4194304;  a.scale[5] = 1.f;
    a.src[6] = (const float*)d_in[6]; a.dst[6] = wkvall + 6291456;  a.scale[6] = 1.f;
    a.src[7] = (const float*)d_in[7]; a.dst[7] = wob;               a.scale[7] = 1.f;
    const int blks[8] = {8192, 8192, 4096, 4096, 2048, 2048, 4096, 4096};
    int acc = 0;
    for (int i = 0; i < 8; ++i) { a.startblk[i] = acc; acc += blks[i]; }

    cast_all_k<<<acc, 256, 0, stream>>>(a);

    // 1D grids (nbm=32 hardcoded in kernel): nwg = 32 * (N/128)
    gemm_bt<0><<<32 * 24, 256, 0, stream>>>(qbf,  wqall,  QCb, QRb, nullptr, 2048);
    gemm_bt<1><<<32 * 40, 256, 0, stream>>>(kvbf, wkvall, KCb, KRb, VTb,     2048);

    flash_attn<<<dim3(16, 16, 2), 256, 0, stream>>>(QCb, QRb, KCb, KRb, VTb, Ob);

    gemm_bt<2><<<32 * 16, 256, 0, stream>>>(Ob, wob, d_out, nullptr, nullptr, 2048);
}

// Round 9
// 471.370 us; speedup vs baseline: 1.6623x; 1.0208x over previous
//
#include <hip/hip_runtime.h>
#include <hip/hip_bf16.h>

typedef unsigned short u16;
typedef unsigned int u32;
typedef unsigned long long u64;
typedef __attribute__((ext_vector_type(8))) short short8;
typedef __attribute__((ext_vector_type(4))) float floatx4;

#if __has_builtin(__builtin_amdgcn_exp2f)
#define EXP2F(x) __builtin_amdgcn_exp2f(x)
#else
#define EXP2F(x) exp2f(x)
#endif

// SCALE * log2(e): softmax runs in base 2, scale pre-folded into Q cast.
#define QSCALE (0.07216878364870323f * 1.4426950408889634f)
#define ROPE_C 0.62286151779f   /* log2(1e6)/32 */

__device__ __forceinline__ u16 f2b(float f) {
    unsigned int x = __builtin_bit_cast(unsigned int, f);
    unsigned int r = (x + 0x7fffu + ((x >> 16) & 1u)) >> 16;   // RNE
    return (u16)r;
}
__device__ __forceinline__ u32 pk2(float a, float b) {
    return (u32)f2b(a) | ((u32)f2b(b) << 16);   // low 16 = a, high 16 = b
}
// HW packed f32->bf16 (RNE): 1 instr replaces ~10 integer VALU ops.
__device__ __forceinline__ u32 cvtpk(float a, float b) {
    u32 r;
    asm("v_cvt_pk_bf16_f32 %0, %1, %2" : "=v"(r) : "v"(a), "v"(b));
    return r;   // low 16 = bf16(a), high 16 = bf16(b)
}
__device__ __forceinline__ void async16(const void* g, void* l) {
    __builtin_amdgcn_global_load_lds(
        (const __attribute__((address_space(1))) void*)g,
        (__attribute__((address_space(3))) void*)l, 16, 0, 0);
}

// ---------------------------------------------------------------- fused cast
struct CastArgs {
    const float* src[8];
    u16* dst[8];
    float scale[8];
    int startblk[8];
};

__global__ void cast_all_k(CastArgs a)
{
    const int bid = blockIdx.x;
    int s = 0;
#pragma unroll
    for (int i = 1; i < 8; ++i) s += (bid >= a.startblk[i]);
    const long idx = ((long)(bid - a.startblk[s]) * 256 + threadIdx.x) * 4;
    const float4 v = *(const float4*)(a.src[s] + idx);
    const float sc = a.scale[s];
    const u64 pk = (u64)pk2(v.x * sc, v.y * sc)
                 | ((u64)pk2(v.z * sc, v.w * sc) << 32);
    *(u64*)(a.dst[s] + idx) = pk;
}

// ---------------------------------------------------------------- GEMM  C = A(MxK) * B(NxK)^T
// Proven 128x128 / 256-thread / 3-blocks-per-CU structure, T1 bijective XCD
// swizzle (1D grid, wid = (id%8)*(nwg/8)+id/8, m-fastest within XCD chunk).
// EPI 0 (Q merged, N=3072): col<2048 -> QC bf16 (ld 2048); col>=2048 -> RoPE -> QR (ld 1024)
// EPI 1 (KV merged, N=5120): col<2048 -> KC; 2048..3071 -> RoPE -> KR; >=3072 -> V transposed (b,hd,n)
// EPI 2 (final, N=2048): f32 row-major
template<int EPI>
__global__ void __launch_bounds__(256, 3)
gemm_bt(const u16* __restrict__ A, const u16* __restrict__ Bw,
        void* __restrict__ out0, u16* __restrict__ out1, u16* __restrict__ out2,
        int K)
{
    __shared__ u16 As[128 * 64];
    __shared__ u16 Bs[128 * 64];
    const int t = threadIdx.x;
    const int w = t >> 6;
    const int lane = t & 63;
    const int lq = lane >> 4, lr = lane & 15;

    // bijective XCD swizzle (all grids are multiples of 8); nbm = 32 (M=4096)
    const int nwg = gridDim.x;
    const int id = blockIdx.x;
    const int wid = (id & 7) * (nwg >> 3) + (id >> 3);
    const long tileM = (long)(wid & 31) << 7;
    const long tileN = (long)(wid >> 5) << 7;

    const int wm = (w >> 1) * 64, wn = (w & 1) * 64;

    const floatx4 fzero = {0.f, 0.f, 0.f, 0.f};
    floatx4 acc[4][4];
#pragma unroll
    for (int i = 0; i < 4; ++i)
#pragma unroll
        for (int j = 0; j < 4; ++j) acc[i][j] = fzero;

    for (int k0 = 0; k0 < K; k0 += 64) {
#pragma unroll
        for (int r = 0; r < 4; ++r) {
            const int c = r * 256 + t;
            const int row = c >> 3, cc = c & 7;
            const int gcol = ((cc ^ (row & 7)) << 3);
            async16(A + (tileM + row) * (long)K + k0 + gcol, (char*)As + c * 16);
        }
#pragma unroll
        for (int r = 0; r < 4; ++r) {
            const int c = r * 256 + t;
            const int row = c >> 3, cc = c & 7;
            const int gcol = ((cc ^ (row & 7)) << 3);
            async16(Bw + (tileN + row) * (long)K + k0 + gcol, (char*)Bs + c * 16);
        }
        __builtin_amdgcn_s_waitcnt(0);
        __syncthreads();
#pragma unroll
        for (int kk = 0; kk < 2; ++kk) {
            short8 af[4], bfr[4];
#pragma unroll
            for (int i = 0; i < 4; ++i) {
                const int row = wm + 16 * i + lr;
                const int cc = (kk * 4 + lq) ^ (row & 7);
                af[i] = *(const short8*)(As + row * 64 + cc * 8);
            }
#pragma unroll
            for (int j = 0; j < 4; ++j) {
                const int row = wn + 16 * j + lr;
                const int cc = (kk * 4 + lq) ^ (row & 7);
                bfr[j] = *(const short8*)(Bs + row * 64 + cc * 8);
            }
            __builtin_amdgcn_s_setprio(1);
#pragma unroll
            for (int i = 0; i < 4; ++i)
#pragma unroll
                for (int j = 0; j < 4; ++j)
                    acc[i][j] = __builtin_amdgcn_mfma_f32_16x16x32_bf16(
                        af[i], bfr[j], acc[i][j], 0, 0, 0);
            __builtin_amdgcn_s_setprio(0);
        }
        __syncthreads();
    }

    // ---- epilogue (region is block-uniform: boundaries are multiples of 128)
    const bool isV    = (EPI == 1) && (tileN >= 3072);
    const bool isRope = (EPI != 2) && !isV && (tileN >= 2048);

#pragma unroll
    for (int i = 0; i < 4; ++i) {
#pragma unroll
        for (int j = 0; j < 4; ++j) {
            const long row0 = tileM + wm + 16 * i + 4 * lq;
            const long col  = tileN + wn + 16 * j + lr;
            if (EPI == 2) {
#pragma unroll
                for (int r = 0; r < 4; ++r)
                    ((float*)out0)[(row0 + r) * 2048 + col] = acc[i][j][r];
            } else if (isV) {
                const u32 lo = pk2(acc[i][j][0], acc[i][j][1]);
                const u32 hi = pk2(acc[i][j][2], acc[i][j][3]);
                const long bb = row0 >> 11;
                u16* dst = out2 + ((bb * 2048 + (col - 3072)) << 11) + (row0 & 2047);
                *(uint2*)dst = make_uint2(lo, hi);
            } else if (isRope) {
                const int jj = ((int)col & 63) >> 1;
                const float freq = EXP2F(-ROPE_C * (float)jj);
#pragma unroll
                for (int r = 0; r < 4; ++r) {
                    const float v = acc[i][j][r];
                    const float vp = __shfl_xor(v, 1, 64);
                    const long row = row0 + r;
                    float sn, cs;
                    __sincosf((float)(row & 2047) * freq, &sn, &cs);
                    const float o = (col & 1) ? (v * cs + vp * sn) : (v * cs - vp * sn);
                    out1[row * 1024 + (col - 2048)] = f2b(o);
                }
            } else {
#pragma unroll
                for (int r = 0; r < 4; ++r)
                    ((u16*)out0)[(row0 + r) * 2048 + col] = f2b(acc[i][j][r]);
            }
        }
    }
}

// ---------------------------------------------------------------- flash attention (S^T dataflow)
// grid (16, 16, 2), 256 threads (4 waves), wave owns a 32-row Q strip.
// XCD remap: h = 2*(x&7) + (y&1), qx = 8*(x>>3) + (y>>1) (bijective) — all 16
// Q-tiles of a head on one XCD so its K/V panels stay in that XCD's L2.
// launch_bounds(256,2): needs ~184 unified regs (120 arch + 64 acc);
// 4 blocks/CU spills the accumulator (round-4: 839MB scratch traffic).
// Single-buffer staging (round-6 form, measured best: 121us; dbuf+counted
// vmcnt measured WORSE, 125us, round-7). LDS 56KB: KC16+KR8+VT16 + DEDICATED
// P 16KB -> no KC alias -> mid-barrier removed (2 __syncthreads per tile).
// P-pack uses v_cvt_pk_bf16_f32 (1 instr per pair vs ~10 integer VALU ops
// for the manual-RNE pk2): removes ~160 VALU instrs per tile per wave.
__global__ void __launch_bounds__(256, 2)
flash_attn(const u16* __restrict__ QC, const u16* __restrict__ QR,
           const u16* __restrict__ KC, const u16* __restrict__ KR,
           const u16* __restrict__ VT, u16* __restrict__ Obuf)
{
    __shared__ u16 KC_s[64 * 128];    // 16KB
    __shared__ u16 KR_s[64 * 64];     // 8KB
    __shared__ u16 VT_s[128 * 64];    // 16KB
    __shared__ u16 P_s[4][2048];      // 16KB, wave-private strips

    const int t = threadIdx.x;
    const int w = t >> 6;
    const int lane = t & 63;
    const int lq = lane >> 4, lr = lane & 15;
    const int bx = blockIdx.x, by = blockIdx.y;
    const int h  = ((bx & 7) << 1) | (by & 1);     // head: fixed x&7 -> fixed XCD
    const int qx = ((bx >> 3) << 3) | (by >> 1);   // Q tile index 0..15
    const int mbase = qx * 128 + w * 32;
    const int b = blockIdx.z;

    // Q fragments (Y-operand layout [m=lane&15][k=lq*8+j]) in registers
    short8 aq[2][6];
#pragma unroll
    for (int i = 0; i < 2; ++i) {
        const long m = mbase + 16 * i + lr;
        const u16* qc = QC + ((long)b * 2048 + m) * 2048 + h * 128;
        const u16* qr = QR + ((long)b * 2048 + m) * 1024 + h * 64;
#pragma unroll
        for (int kc = 0; kc < 4; ++kc) aq[i][kc]     = *(const short8*)(qc + kc * 32 + lq * 8);
#pragma unroll
        for (int kc = 0; kc < 2; ++kc) aq[i][4 + kc] = *(const short8*)(qr + kc * 32 + lq * 8);
    }

    const floatx4 fzero = {0.f, 0.f, 0.f, 0.f};
    float mst[2], lst[2];
    floatx4 oacc[2][8];   // O^T: rows d (tile jn, 4lq+r), cols m = lr (strip i)
#pragma unroll
    for (int i = 0; i < 2; ++i) {
        mst[i] = -1e30f; lst[i] = 0.f;
#pragma unroll
        for (int jn = 0; jn < 8; ++jn) oacc[i][jn] = fzero;
    }

    const u16* kc_g = KC + ((long)b * 2048) * 2048 + h * 128;
    const u16* kr_g = KR + ((long)b * 2048) * 1024 + h * 64;
    const u16* vt_g = VT + ((long)(b * 16 + h) * 128) * 2048;

    for (int kt = 0; kt < 32; ++kt) {
#pragma unroll
        for (int r = 0; r < 4; ++r) {
            const int c = r * 256 + t;
            const int krow = c >> 4, cc = c & 15;
            const int gc = cc ^ (krow & 7);
            async16(kc_g + (long)(kt * 64 + krow) * 2048 + gc * 8, (char*)KC_s + c * 16);
        }
#pragma unroll
        for (int r = 0; r < 2; ++r) {
            const int c = r * 256 + t;
            const int krow = c >> 3, cc = c & 7;
            const int gc = cc ^ (krow & 7);
            async16(kr_g + (long)(kt * 64 + krow) * 1024 + gc * 8, (char*)KR_s + c * 16);
        }
#pragma unroll
        for (int r = 0; r < 4; ++r) {
            const int c = r * 256 + t;
            const int drow = c >> 3, cc = c & 7;
            const int gc = cc ^ (drow & 7);
            async16(vt_g + (long)drow * 2048 + kt * 64 + gc * 8, (char*)VT_s + c * 16);
        }
        __builtin_amdgcn_s_waitcnt(0);
        __syncthreads();

        // ---- S^T = K Q^T: sT[j][i] rows n (16j+4lq+r), cols m (16i, lane lr)
        floatx4 sT[4][2];
#pragma unroll
        for (int j = 0; j < 4; ++j)
#pragma unroll
            for (int i = 0; i < 2; ++i) sT[j][i] = fzero;
#pragma unroll
        for (int kc = 0; kc < 6; ++kc) {
            short8 kf[4];
#pragma unroll
            for (int j = 0; j < 4; ++j) {
                const int krow = 16 * j + lr;
                if (kc < 4) {
                    const int cc = (4 * kc + lq) ^ (krow & 7);
                    kf[j] = *(const short8*)(KC_s + krow * 128 + cc * 8);
                } else {
                    const int cc = (4 * (kc - 4) + lq) ^ (krow & 7);
                    kf[j] = *(const short8*)(KR_s + krow * 64 + cc * 8);
                }
            }
            __builtin_amdgcn_s_setprio(1);
#pragma unroll
            for (int j = 0; j < 4; ++j)
#pragma unroll
                for (int i = 0; i < 2; ++i)
                    sT[j][i] = __builtin_amdgcn_mfma_f32_16x16x32_bf16(
                        kf[j], aq[i][kc], sT[j][i], 0, 0, 0);
            __builtin_amdgcn_s_setprio(0);
        }

        // ---- online softmax: per-lane over 16 regs, then 2 shuffle rounds (lq groups)
        float rmax[2];
#pragma unroll
        for (int i = 0; i < 2; ++i) {
            float a0 = fmaxf(fmaxf(sT[0][i][0], sT[0][i][1]), fmaxf(sT[0][i][2], sT[0][i][3]));
            float a1 = fmaxf(fmaxf(sT[1][i][0], sT[1][i][1]), fmaxf(sT[1][i][2], sT[1][i][3]));
            float a2 = fmaxf(fmaxf(sT[2][i][0], sT[2][i][1]), fmaxf(sT[2][i][2], sT[2][i][3]));
            float a3 = fmaxf(fmaxf(sT[3][i][0], sT[3][i][1]), fmaxf(sT[3][i][2], sT[3][i][3]));
            rmax[i] = fmaxf(fmaxf(a0, a1), fmaxf(a2, a3));
        }
#pragma unroll
        for (int i = 0; i < 2; ++i) {
            rmax[i] = fmaxf(rmax[i], __shfl_xor(rmax[i], 16, 64));
            rmax[i] = fmaxf(rmax[i], __shfl_xor(rmax[i], 32, 64));
        }

        // T13 defer-max: only rescale when max grew by >8 (P bounded by 2^8, bf16-safe)
        const int upd = (rmax[0] > mst[0] + 8.f) | (rmax[1] > mst[1] + 8.f);
        if (__any(upd)) {
#pragma unroll
            for (int i = 0; i < 2; ++i) {
                const float mnew = fmaxf(mst[i], rmax[i]);
                const float alpha = EXP2F(mst[i] - mnew);
                mst[i] = mnew;
                lst[i] *= alpha;
#pragma unroll
                for (int jn = 0; jn < 8; ++jn)
#pragma unroll
                    for (int r = 0; r < 4; ++r) oacc[i][jn][r] *= alpha;
            }
        }

        float rsum[2] = {0.f, 0.f};
#pragma unroll
        for (int j = 0; j < 4; ++j)
#pragma unroll
            for (int i = 0; i < 2; ++i)
#pragma unroll
                for (int r = 0; r < 4; ++r) {
                    const float p = EXP2F(sT[j][i][r] - mst[i]);
                    sT[j][i][r] = p;
                    rsum[i] += p;
                }
#pragma unroll
        for (int i = 0; i < 2; ++i) {
            rsum[i] += __shfl_xor(rsum[i], 16, 64);
            rsum[i] += __shfl_xor(rsum[i], 32, 64);
            lst[i] += rsum[i];
        }

        // ---- write P strip (dedicated, wave-private -> no barrier needed):
        // [row=16i+lr][col 8-blocks XOR row&7], stride 64; HW packed cvt.
        u16* pw = &P_s[w][0];
#pragma unroll
        for (int i = 0; i < 2; ++i)
#pragma unroll
            for (int j = 0; j < 4; ++j) {
                const int row = 16 * i + lr;
                const int c8 = (2 * j + (lq >> 1)) ^ (row & 7);
                const u32 d0 = cvtpk(sT[j][i][0], sT[j][i][1]);
                const u32 d1 = cvtpk(sT[j][i][2], sT[j][i][3]);
                *(uint2*)(pw + row * 64 + c8 * 8 + 4 * (lq & 1)) = make_uint2(d0, d1);
            }

        // ---- O^T += V^T P^T: mfma(V-frag, P-frag)
#pragma unroll
        for (int kc = 0; kc < 2; ++kc) {
            short8 ap[2];
#pragma unroll
            for (int i = 0; i < 2; ++i) {
                const int row = 16 * i + lr;
                ap[i] = *(const short8*)(pw + row * 64 + (((4 * kc + lq) ^ (row & 7)) << 3));
            }
            __builtin_amdgcn_s_setprio(1);
#pragma unroll
            for (int jn = 0; jn < 8; ++jn) {
                const int drow = 16 * jn + lr;
                const int cc = (4 * kc + lq) ^ (drow & 7);
                const short8 bv = *(const short8*)(VT_s + drow * 64 + cc * 8);
#pragma unroll
                for (int i = 0; i < 2; ++i)
                    oacc[i][jn] = __builtin_amdgcn_mfma_f32_16x16x32_bf16(
                        bv, ap[i], oacc[i][jn], 0, 0, 0);
            }
            __builtin_amdgcn_s_setprio(0);
        }
        __syncthreads();
    }

    // ---- epilogue: O^T / l -> bf16, 8B packed stores (4 consecutive d)
#pragma unroll
    for (int i = 0; i < 2; ++i) {
        const float rl = 1.0f / lst[i];
        const long row = (long)b * 2048 + mbase + 16 * i + lr;
#pragma unroll
        for (int jn = 0; jn < 8; ++jn) {
            const u32 lo = pk2(oacc[i][jn][0] * rl, oacc[i][jn][1] * rl);
            const u32 hi = pk2(oacc[i][jn][2] * rl, oacc[i][jn][3] * rl);
            u16* dst = Obuf + row * 2048 + h * 128 + 16 * jn + 4 * lq;
            *(uint2*)dst = make_uint2(lo, hi);
        }
    }
}

// ---------------------------------------------------------------- launch
extern "C" void kernel_launch(void* const* d_in, const int* in_sizes, int n_in,
                              void* d_out, int out_size, void* d_ws, size_t ws_size,
                              hipStream_t stream)
{
    (void)in_sizes; (void)n_in; (void)out_size; (void)ws_size;

    u16* p = (u16*)d_ws;
    u16* qbf   = p; p += 8388608;
    u16* kvbf  = p; p += 8388608;
    u16* wqall = p; p += 6291456;   // rows 0..2047 = W_QC, 2048..3071 = W_QR
    u16* wkvall= p; p += 10485760;  // rows 0..2047 = W_KC, 2048..3071 = W_KR, 3072..5119 = W_V
    u16* wob   = p; p += 4194304;
    u16* QCb   = p; p += 8388608;
    u16* QRb   = p; p += 4194304;
    u16* KCb   = p; p += 8388608;
    u16* KRb   = p; p += 4194304;
    u16* VTb   = p; p += 8388608;
    u16* Ob    = p; p += 8388608;

    CastArgs a;
    a.src[0] = (const float*)d_in[0]; a.dst[0] = qbf;               a.scale[0] = QSCALE;
    a.src[1] = (const float*)d_in[1]; a.dst[1] = kvbf;              a.scale[1] = 1.f;
    a.src[2] = (const float*)d_in[2]; a.dst[2] = wqall;             a.scale[2] = 1.f;
    a.src[3] = (const float*)d_in[3]; a.dst[3] = wkvall;            a.scale[3] = 1.f;
    a.src[4] = (const float*)d_in[4]; a.dst[4] = wqall + 4194304;   a.scale[4] = 1.f;
    a.src[5] = (const float*)d_in[5]; a.dst[5] = wkvall + 4194304;  a.scale[5] = 1.f;
    a.src[6] = (const float*)d_in[6]; a.dst[6] = wkvall + 6291456;  a.scale[6] = 1.f;
    a.src[7] = (const float*)d_in[7]; a.dst[7] = wob;               a.scale[7] = 1.f;
    const int blks[8] = {8192, 8192, 4096, 4096, 2048, 2048, 4096, 4096};
    int acc = 0;
    for (int i = 0; i < 8; ++i) { a.startblk[i] = acc; acc += blks[i]; }

    cast_all_k<<<acc, 256, 0, stream>>>(a);

    // 1D grids (nbm=32 hardcoded in kernel): nwg = 32 * (N/128)
    gemm_bt<0><<<32 * 24, 256, 0, stream>>>(qbf,  wqall,  QCb, QRb, nullptr, 2048);
    gemm_bt<1><<<32 * 40, 256, 0, stream>>>(kvbf, wkvall, KCb, KRb, VTb,     2048);

    flash_attn<<<dim3(16, 16, 2), 256, 0, stream>>>(QCb, QRb, KCb, KRb, VTb, Ob);

    gemm_bt<2><<<32 * 16, 256, 0, stream>>>(Ob, wob, d_out, nullptr, nullptr, 2048);
}